// Round 1
// baseline (437.202 us; speedup 1.0000x reference)
//
#include <hip/hip_runtime.h>
#include <math.h>

#define NHID 1024
#define NOUT 50257
#define MAXLEN 24

// ws layout (float offsets)
#define WS_APP   0        // attn_applied [1024]
#define WS_OUT   1024     // comb output, pre-relu [1024]
#define WS_H     2048     // h_new [1024]
#define WS_LOGIT 4096     // logits [50257]
#define WS_PAIRS 56320    // 256 (m,s) pairs = 512 floats

__device__ __forceinline__ float wave_reduce_sum(float v) {
    #pragma unroll
    for (int off = 32; off > 0; off >>= 1) v += __shfl_down(v, off, 64);
    return v;
}

__device__ __forceinline__ void lse_merge(float& m, float& s, float m2, float s2) {
    float M = fmaxf(m, m2);
    s = s * expf(m - M) + s2 * expf(m2 - M);
    m = M;
}

// K1: attention scores + softmax + attn_applied. One block, 256 threads.
__global__ void k_attn(const int* __restrict__ inp, const float* __restrict__ hid,
                       const float* __restrict__ enc, const float* __restrict__ embW,
                       const float* __restrict__ attnW, const float* __restrict__ attnb,
                       float* __restrict__ ws, float* __restrict__ out) {
    __shared__ float s_sc[MAXLEN];
    __shared__ float s_w[MAXLEN];
    const int tid = threadIdx.x;
    const int lane = tid & 63, wave = tid >> 6;
    const float4* emb4 = (const float4*)(embW + (size_t)inp[0] * NHID);
    const float4* hid4 = (const float4*)hid;
    for (int i = wave; i < MAXLEN; i += 4) {
        const float4* w4 = (const float4*)(attnW + (size_t)i * 2 * NHID);
        float acc = 0.f;
        #pragma unroll
        for (int it = 0; it < 8; ++it) {
            int idx = it * 64 + lane;                       // float4 idx in [0,512)
            float4 w = w4[idx];
            float4 a = (idx < 256) ? emb4[idx] : hid4[idx - 256];
            acc += w.x * a.x + w.y * a.y + w.z * a.z + w.w * a.w;
        }
        acc = wave_reduce_sum(acc);
        if (lane == 0) s_sc[i] = acc + attnb[i];
    }
    __syncthreads();
    if (tid == 0) {
        float m = -1e30f;
        for (int i = 0; i < MAXLEN; ++i) m = fmaxf(m, s_sc[i]);
        float s = 0.f;
        for (int i = 0; i < MAXLEN; ++i) { float e = expf(s_sc[i] - m); s_w[i] = e; s += e; }
        float inv = 1.f / s;
        for (int i = 0; i < MAXLEN; ++i) { s_w[i] *= inv; out[NOUT + NHID + i] = s_w[i]; }
    }
    __syncthreads();
    for (int j = tid; j < NHID; j += 256) {
        float acc = 0.f;
        #pragma unroll 4
        for (int i = 0; i < MAXLEN; ++i) acc += s_w[i] * enc[i * NHID + j];
        ws[WS_APP + j] = acc;
    }
}

// K2: out[j] = dot(concat(emb, attn_applied), comb_W[j]) + comb_b[j]. One block per row.
__global__ void k_comb(const int* __restrict__ inp, const float* __restrict__ embW,
                       const float* __restrict__ combW, const float* __restrict__ combb,
                       float* __restrict__ ws) {
    const int j = blockIdx.x, t = threadIdx.x;
    const float4* emb4 = (const float4*)(embW + (size_t)inp[0] * NHID);
    const float4* app4 = (const float4*)(ws + WS_APP);
    const float4* w4 = (const float4*)(combW + (size_t)j * 2 * NHID);
    float4 wa = w4[t],       xa = emb4[t];
    float4 wb = w4[256 + t], xb = app4[t];
    float p = wa.x * xa.x + wa.y * xa.y + wa.z * xa.z + wa.w * xa.w
            + wb.x * xb.x + wb.y * xb.y + wb.z * xb.z + wb.w * xb.w;
    p = wave_reduce_sum(p);
    __shared__ float s_r[4];
    if ((t & 63) == 0) s_r[t >> 6] = p;
    __syncthreads();
    if (t == 0) ws[WS_OUT + j] = s_r[0] + s_r[1] + s_r[2] + s_r[3] + combb[j];
}

// K3: GRU step, one block per hidden index j (6 dot products of length 1024).
__global__ void k_gru(const float* __restrict__ hid, const float* __restrict__ Wih,
                      const float* __restrict__ Whh, const float* __restrict__ bih,
                      const float* __restrict__ bhh, float* __restrict__ ws,
                      float* __restrict__ out) {
    const int j = blockIdx.x, t = threadIdx.x;
    const float4* x4 = (const float4*)(ws + WS_OUT);
    const float4* h4 = (const float4*)hid;
    float4 xv = x4[t];
    xv.x = fmaxf(xv.x, 0.f); xv.y = fmaxf(xv.y, 0.f);
    xv.z = fmaxf(xv.z, 0.f); xv.w = fmaxf(xv.w, 0.f);
    float4 hv = h4[t];
    float p[6];
    #pragma unroll
    for (int r = 0; r < 3; ++r) {
        float4 wv = ((const float4*)(Wih + (size_t)(r * NHID + j) * NHID))[t];
        p[r] = wv.x * xv.x + wv.y * xv.y + wv.z * xv.z + wv.w * xv.w;
    }
    #pragma unroll
    for (int r = 0; r < 3; ++r) {
        float4 wv = ((const float4*)(Whh + (size_t)(r * NHID + j) * NHID))[t];
        p[3 + r] = wv.x * hv.x + wv.y * hv.y + wv.z * hv.z + wv.w * hv.w;
    }
    __shared__ float s_r[6][4];
    #pragma unroll
    for (int r = 0; r < 6; ++r) {
        float v = wave_reduce_sum(p[r]);
        if ((t & 63) == 0) s_r[r][t >> 6] = v;
    }
    __syncthreads();
    if (t == 0) {
        float g[6];
        #pragma unroll
        for (int r = 0; r < 6; ++r) g[r] = s_r[r][0] + s_r[r][1] + s_r[r][2] + s_r[r][3];
        float ir = g[0] + bih[j],            hr = g[3] + bhh[j];
        float iz = g[1] + bih[NHID + j],     hz = g[4] + bhh[NHID + j];
        float in_ = g[2] + bih[2 * NHID + j], hn = g[5] + bhh[2 * NHID + j];
        float r_ = 1.f / (1.f + expf(-(ir + hr)));
        float z_ = 1.f / (1.f + expf(-(iz + hz)));
        float n_ = tanhf(in_ + r_ * hn);
        float hnew = (1.f - z_) * n_ + z_ * hid[j];
        ws[WS_H + j] = hnew;
        out[NOUT + j] = hnew;
    }
}

// K4: logits[row] = dot(h_new, out_W[row]) + out_b[row]. One wave per row.
__global__ void k_logits(const float* __restrict__ outW, const float* __restrict__ outb,
                         float* __restrict__ ws) {
    const int lane = threadIdx.x & 63, wave = threadIdx.x >> 6;
    const int row = blockIdx.x * 4 + wave;
    if (row >= NOUT) return;
    const float4* w4 = (const float4*)(outW + (size_t)row * NHID);
    const float4* h4 = (const float4*)(ws + WS_H);
    float acc = 0.f;
    #pragma unroll
    for (int it = 0; it < 4; ++it) {
        int idx = it * 64 + lane;
        float4 w = w4[idx], h = h4[idx];
        acc += w.x * h.x + w.y * h.y + w.z * h.z + w.w * h.w;
    }
    acc = wave_reduce_sum(acc);
    if (lane == 0) ws[WS_LOGIT + row] = acc + outb[row];
}

// K5: per-block online logsumexp partials over logits -> 256 (m,s) pairs.
__global__ void k_lse_partial(const float* __restrict__ logits, float* __restrict__ pairs) {
    const int tid = threadIdx.x;
    const int i = blockIdx.x * 256 + tid;
    float m = -1e30f, s = 0.f;
    if (i < NOUT) { m = logits[i]; s = 1.f; }
    #pragma unroll
    for (int off = 32; off > 0; off >>= 1) {
        float m2 = __shfl_down(m, off, 64);
        float s2 = __shfl_down(s, off, 64);
        lse_merge(m, s, m2, s2);
    }
    __shared__ float sm[4], ss[4];
    if ((tid & 63) == 0) { sm[tid >> 6] = m; ss[tid >> 6] = s; }
    __syncthreads();
    if (tid == 0) {
        float M = sm[0], S = ss[0];
        lse_merge(M, S, sm[1], ss[1]);
        lse_merge(M, S, sm[2], ss[2]);
        lse_merge(M, S, sm[3], ss[3]);
        pairs[2 * blockIdx.x] = M;
        pairs[2 * blockIdx.x + 1] = S;
    }
}

// K6: each block re-merges the 256 pairs -> C = M + log(S); logp = logits - C.
__global__ void k_finalize(const float* __restrict__ logits, const float* __restrict__ pairs,
                           float* __restrict__ out) {
    const int tid = threadIdx.x;
    float m = pairs[2 * tid], s = pairs[2 * tid + 1];
    #pragma unroll
    for (int off = 32; off > 0; off >>= 1) {
        float m2 = __shfl_down(m, off, 64);
        float s2 = __shfl_down(s, off, 64);
        lse_merge(m, s, m2, s2);
    }
    __shared__ float sm[4], ss[4];
    __shared__ float sC;
    if ((tid & 63) == 0) { sm[tid >> 6] = m; ss[tid >> 6] = s; }
    __syncthreads();
    if (tid == 0) {
        float M = sm[0], S = ss[0];
        lse_merge(M, S, sm[1], ss[1]);
        lse_merge(M, S, sm[2], ss[2]);
        lse_merge(M, S, sm[3], ss[3]);
        sC = M + logf(S);
    }
    __syncthreads();
    const float C = sC;
    const int i = blockIdx.x * 256 + tid;
    if (i < NOUT) out[i] = logits[i] - C;
}

extern "C" void kernel_launch(void* const* d_in, const int* in_sizes, int n_in,
                              void* d_out, int out_size, void* d_ws, size_t ws_size,
                              hipStream_t stream) {
    const int*   inp   = (const int*)d_in[0];
    const float* hid   = (const float*)d_in[1];
    // d_in[2] (encoder_output) is unused by the reference.
    const float* enc   = (const float*)d_in[3];
    const float* embW  = (const float*)d_in[4];
    const float* attnW = (const float*)d_in[5];
    const float* attnb = (const float*)d_in[6];
    const float* combW = (const float*)d_in[7];
    const float* combb = (const float*)d_in[8];
    const float* Wih   = (const float*)d_in[9];
    const float* Whh   = (const float*)d_in[10];
    const float* bih   = (const float*)d_in[11];
    const float* bhh   = (const float*)d_in[12];
    const float* outW  = (const float*)d_in[13];
    const float* outb  = (const float*)d_in[14];
    float* out = (float*)d_out;
    float* ws  = (float*)d_ws;

    hipLaunchKernelGGL(k_attn, dim3(1), dim3(256), 0, stream,
                       inp, hid, enc, embW, attnW, attnb, ws, out);
    hipLaunchKernelGGL(k_comb, dim3(NHID), dim3(256), 0, stream,
                       inp, embW, combW, combb, ws);
    hipLaunchKernelGGL(k_gru, dim3(NHID), dim3(256), 0, stream,
                       hid, Wih, Whh, bih, bhh, ws, out);
    hipLaunchKernelGGL(k_logits, dim3((NOUT + 3) / 4), dim3(256), 0, stream,
                       outW, outb, ws);
    hipLaunchKernelGGL(k_lse_partial, dim3(256), dim3(256), 0, stream,
                       ws + WS_LOGIT, ws + WS_PAIRS);
    hipLaunchKernelGGL(k_finalize, dim3(256), dim3(256), 0, stream,
                       ws + WS_LOGIT, ws + WS_PAIRS, out);
}

// Round 2
// 426.473 us; speedup vs baseline: 1.0252x; 1.0252x over previous
//
#include <hip/hip_runtime.h>
#include <math.h>

#define NHID 1024
#define NOUT 50257
#define MAXLEN 24

// ws layout (float offsets)
#define WS_APP   0        // attn_applied [1024]
#define WS_X     1024     // relu(comb out) [1024]
#define WS_GH    2048     // W_hh @ h + b_hh [3072]
#define WS_H     5120     // h_new [1024]
#define WS_LOGIT 8192     // logits [50257]
#define WS_PAIRS 61440    // 786 (m,s) pairs

#define LOG_BLOCKS 786    // ceil(50257 / 64)

__device__ __forceinline__ float wave_reduce_sum(float v) {
    #pragma unroll
    for (int off = 32; off > 0; off >>= 1) v += __shfl_down(v, off, 64);
    return v;
}

__device__ __forceinline__ void lse_merge(float& m, float& s, float m2, float s2) {
    float M = fmaxf(m, m2);
    s = s * expf(m - M) + s2 * expf(m2 - M);
    m = M;
}

// K1: block 0 = attention (scores+softmax+applied); blocks 1.. = gh rows.
__global__ __launch_bounds__(1024) void
k_attn_gh(const int* __restrict__ inp, const float* __restrict__ hid,
          const float* __restrict__ enc, const float* __restrict__ embW,
          const float* __restrict__ attnW, const float* __restrict__ attnb,
          const float* __restrict__ Whh, const float* __restrict__ bhh,
          float* __restrict__ ws, float* __restrict__ out) {
    const int tid = threadIdx.x;
    const int lane = tid & 63, wave = tid >> 6;
    const float4* hid4 = (const float4*)hid;

    if (blockIdx.x > 0) {
        // gh: one wave per row, 16 rows per block. rows 0..3071
        const int row = (blockIdx.x - 1) * 16 + wave;
        const float4* w4 = (const float4*)(Whh + (size_t)row * NHID);
        float acc = 0.f;
        #pragma unroll
        for (int it = 0; it < 4; ++it) {
            int idx = it * 64 + lane;
            float4 w = w4[idx], h = hid4[idx];
            acc += w.x * h.x + w.y * h.y + w.z * h.z + w.w * h.w;
        }
        acc = wave_reduce_sum(acc);
        if (lane == 0) ws[WS_GH + row] = acc + bhh[row];
        return;
    }

    __shared__ float s_sc[MAXLEN];
    __shared__ float s_w[MAXLEN];
    const float4* emb4 = (const float4*)(embW + (size_t)inp[0] * NHID);
    // scores: 16 waves cover 24 rows
    for (int i = wave; i < MAXLEN; i += 16) {
        const float4* w4 = (const float4*)(attnW + (size_t)i * 2 * NHID);
        float acc = 0.f;
        #pragma unroll
        for (int it = 0; it < 8; ++it) {
            int idx = it * 64 + lane;                     // [0,512) float4
            float4 w = w4[idx];
            float4 a = (idx < 256) ? emb4[idx] : hid4[idx - 256];
            acc += w.x * a.x + w.y * a.y + w.z * a.z + w.w * a.w;
        }
        acc = wave_reduce_sum(acc);
        if (lane == 0) s_sc[i] = acc + attnb[i];
    }
    __syncthreads();
    if (tid == 0) {
        float m = -1e30f;
        for (int i = 0; i < MAXLEN; ++i) m = fmaxf(m, s_sc[i]);
        float s = 0.f;
        for (int i = 0; i < MAXLEN; ++i) { float e = expf(s_sc[i] - m); s_w[i] = e; s += e; }
        float inv = 1.f / s;
        for (int i = 0; i < MAXLEN; ++i) { s_w[i] *= inv; out[NOUT + NHID + i] = s_w[i]; }
    }
    __syncthreads();
    {   // applied: thread j computes attn_applied[j]
        float acc = 0.f;
        #pragma unroll 4
        for (int i = 0; i < MAXLEN; ++i) acc += s_w[i] * enc[i * NHID + tid];
        ws[WS_APP + tid] = acc;
    }
}

// K2: x[j] = relu(dot(concat(emb, applied), comb_W[j]) + comb_b[j]).
__global__ __launch_bounds__(256) void
k_comb(const int* __restrict__ inp, const float* __restrict__ embW,
       const float* __restrict__ combW, const float* __restrict__ combb,
       float* __restrict__ ws) {
    const int j = blockIdx.x, t = threadIdx.x;
    const float4* emb4 = (const float4*)(embW + (size_t)inp[0] * NHID);
    const float4* app4 = (const float4*)(ws + WS_APP);
    const float4* w4 = (const float4*)(combW + (size_t)j * 2 * NHID);
    float4 wa = w4[t],       xa = emb4[t];
    float4 wb = w4[256 + t], xb = app4[t];
    float p = wa.x * xa.x + wa.y * xa.y + wa.z * xa.z + wa.w * xa.w
            + wb.x * xb.x + wb.y * xb.y + wb.z * xb.z + wb.w * xb.w;
    p = wave_reduce_sum(p);
    __shared__ float s_r[4];
    if ((t & 63) == 0) s_r[t >> 6] = p;
    __syncthreads();
    if (t == 0) ws[WS_X + j] = fmaxf(s_r[0] + s_r[1] + s_r[2] + s_r[3] + combb[j], 0.f);
}

// K3: gi rows for index j + elementwise GRU combine (gh precomputed in K1).
__global__ __launch_bounds__(256) void
k_gru(const float* __restrict__ hid, const float* __restrict__ Wih,
      const float* __restrict__ bih, float* __restrict__ ws,
      float* __restrict__ out) {
    const int j = blockIdx.x, t = threadIdx.x;
    const float4* x4 = (const float4*)(ws + WS_X);
    float4 xv = x4[t];
    float p[3];
    #pragma unroll
    for (int r = 0; r < 3; ++r) {
        float4 wv = ((const float4*)(Wih + (size_t)(r * NHID + j) * NHID))[t];
        p[r] = wv.x * xv.x + wv.y * xv.y + wv.z * xv.z + wv.w * xv.w;
    }
    __shared__ float s_r[3][4];
    #pragma unroll
    for (int r = 0; r < 3; ++r) {
        float v = wave_reduce_sum(p[r]);
        if ((t & 63) == 0) s_r[r][t >> 6] = v;
    }
    __syncthreads();
    if (t == 0) {
        float gi[3];
        #pragma unroll
        for (int r = 0; r < 3; ++r) gi[r] = s_r[r][0] + s_r[r][1] + s_r[r][2] + s_r[r][3] + bih[r * NHID + j];
        float hr = ws[WS_GH + j], hz = ws[WS_GH + NHID + j], hn = ws[WS_GH + 2 * NHID + j];
        float r_ = 1.f / (1.f + expf(-(gi[0] + hr)));
        float z_ = 1.f / (1.f + expf(-(gi[1] + hz)));
        float n_ = tanhf(gi[2] + r_ * hn);
        float hnew = (1.f - z_) * n_ + z_ * hid[j];
        ws[WS_H + j] = hnew;
        out[NOUT + j] = hnew;
    }
}

// K4: logits + per-block online-LSE pair. 16 waves/block, 4 rows/wave.
__global__ __launch_bounds__(1024) void
k_logits(const float* __restrict__ outW, const float* __restrict__ outb,
         float* __restrict__ ws) {
    const int tid = threadIdx.x;
    const int lane = tid & 63, wave = tid >> 6;
    const float4* h4 = (const float4*)(ws + WS_H);
    float4 hv[4];
    #pragma unroll
    for (int it = 0; it < 4; ++it) hv[it] = h4[it * 64 + lane];
    float m = -1e30f, s = 0.f;
    const int rowBase = blockIdx.x * 64 + wave * 4;
    #pragma unroll
    for (int rr = 0; rr < 4; ++rr) {
        const int row = rowBase + rr;
        if (row >= NOUT) break;
        const float4* w4 = (const float4*)(outW + (size_t)row * NHID);
        float acc = 0.f;
        #pragma unroll
        for (int it = 0; it < 4; ++it) {
            float4 w = w4[it * 64 + lane];
            acc += w.x * hv[it].x + w.y * hv[it].y + w.z * hv[it].z + w.w * hv[it].w;
        }
        acc = wave_reduce_sum(acc);
        if (lane == 0) {
            float v = acc + outb[row];
            ws[WS_LOGIT + row] = v;
            lse_merge(m, s, v, 1.f);
        }
    }
    __shared__ float sm[16], ss[16];
    if (lane == 0) { sm[wave] = m; ss[wave] = s; }
    __syncthreads();
    if (tid == 0) {
        float M = sm[0], S = ss[0];
        #pragma unroll
        for (int w = 1; w < 16; ++w) lse_merge(M, S, sm[w], ss[w]);
        ws[WS_PAIRS + 2 * blockIdx.x] = M;
        ws[WS_PAIRS + 2 * blockIdx.x + 1] = S;
    }
}

// K5: every block merges all pairs -> C, then normalizes its slice.
__global__ __launch_bounds__(1024) void
k_finalize(const float* __restrict__ ws, float* __restrict__ out) {
    const int tid = threadIdx.x;
    const int lane = tid & 63, wave = tid >> 6;
    float m = -1e30f, s = 0.f;
    if (tid < LOG_BLOCKS) { m = ws[WS_PAIRS + 2 * tid]; s = ws[WS_PAIRS + 2 * tid + 1]; }
    #pragma unroll
    for (int off = 32; off > 0; off >>= 1) {
        float m2 = __shfl_down(m, off, 64);
        float s2 = __shfl_down(s, off, 64);
        lse_merge(m, s, m2, s2);
    }
    __shared__ float sm[16], ss[16];
    __shared__ float sC;
    if (lane == 0) { sm[wave] = m; ss[wave] = s; }
    __syncthreads();
    if (tid == 0) {
        float M = sm[0], S = ss[0];
        #pragma unroll
        for (int w = 1; w < 16; ++w) lse_merge(M, S, sm[w], ss[w]);
        sC = M + logf(S);
    }
    __syncthreads();
    const float C = sC;
    const int i = blockIdx.x * 1024 + tid;
    if (i < NOUT) out[i] = ws[WS_LOGIT + i] - C;
}

extern "C" void kernel_launch(void* const* d_in, const int* in_sizes, int n_in,
                              void* d_out, int out_size, void* d_ws, size_t ws_size,
                              hipStream_t stream) {
    const int*   inp   = (const int*)d_in[0];
    const float* hid   = (const float*)d_in[1];
    // d_in[2] (encoder_output) unused by the reference.
    const float* enc   = (const float*)d_in[3];
    const float* embW  = (const float*)d_in[4];
    const float* attnW = (const float*)d_in[5];
    const float* attnb = (const float*)d_in[6];
    const float* combW = (const float*)d_in[7];
    const float* combb = (const float*)d_in[8];
    const float* Wih   = (const float*)d_in[9];
    const float* Whh   = (const float*)d_in[10];
    const float* bih   = (const float*)d_in[11];
    const float* bhh   = (const float*)d_in[12];
    const float* outW  = (const float*)d_in[13];
    const float* outb  = (const float*)d_in[14];
    float* out = (float*)d_out;
    float* ws  = (float*)d_ws;

    hipLaunchKernelGGL(k_attn_gh, dim3(1 + 192), dim3(1024), 0, stream,
                       inp, hid, enc, embW, attnW, attnb, Whh, bhh, ws, out);
    hipLaunchKernelGGL(k_comb, dim3(NHID), dim3(256), 0, stream,
                       inp, embW, combW, combb, ws);
    hipLaunchKernelGGL(k_gru, dim3(NHID), dim3(256), 0, stream,
                       hid, Wih, bih, ws, out);
    hipLaunchKernelGGL(k_logits, dim3(LOG_BLOCKS), dim3(1024), 0, stream,
                       outW, outb, ws);
    hipLaunchKernelGGL(k_finalize, dim3(50), dim3(1024), 0, stream,
                       ws, out);
}

// Round 3
// 425.908 us; speedup vs baseline: 1.0265x; 1.0013x over previous
//
#include <hip/hip_runtime.h>
#include <math.h>

#define NHID 1024
#define NOUT 50257
#define MAXLEN 24

// ws layout (float offsets)
#define WS_APP   0        // attn_applied [1024]
#define WS_X     1024     // relu(comb out) [1024]
#define WS_GH    2048     // W_hh @ h + b_hh [3072]
#define WS_H     5120     // h_new [1024]
#define WS_LOGIT 8192     // logits [50257]
#define WS_PAIRS 61440    // 786 (m,s) pairs

#define LOG_BLOCKS 786    // ceil(50257 / 64)

__device__ __forceinline__ float wave_reduce_sum(float v) {
    #pragma unroll
    for (int off = 32; off > 0; off >>= 1) v += __shfl_down(v, off, 64);
    return v;
}

__device__ __forceinline__ void lse_merge(float& m, float& s, float m2, float s2) {
    float M = fmaxf(m, m2);
    s = s * expf(m - M) + s2 * expf(m2 - M);
    m = M;
}

// K1: block 0 = attention (scores+softmax+applied); blocks 1.. = gh rows.
__global__ __launch_bounds__(1024) void
k_attn_gh(const int* __restrict__ inp, const float* __restrict__ hid,
          const float* __restrict__ enc, const float* __restrict__ embW,
          const float* __restrict__ attnW, const float* __restrict__ attnb,
          const float* __restrict__ Whh, const float* __restrict__ bhh,
          float* __restrict__ ws, float* __restrict__ out) {
    const int tid = threadIdx.x;
    const int lane = tid & 63, wave = tid >> 6;
    const float4* hid4 = (const float4*)hid;

    if (blockIdx.x > 0) {
        // gh: one wave per row, 16 rows per block. rows 0..3071
        const int row = (blockIdx.x - 1) * 16 + wave;
        const float4* w4 = (const float4*)(Whh + (size_t)row * NHID);
        float4 w[4], h[4];
        #pragma unroll
        for (int it = 0; it < 4; ++it) { w[it] = w4[it * 64 + lane]; h[it] = hid4[it * 64 + lane]; }
        float acc = 0.f;
        #pragma unroll
        for (int it = 0; it < 4; ++it)
            acc += w[it].x * h[it].x + w[it].y * h[it].y + w[it].z * h[it].z + w[it].w * h[it].w;
        acc = wave_reduce_sum(acc);
        if (lane == 0) ws[WS_GH + row] = acc + bhh[row];
        return;
    }

    __shared__ float s_sc[MAXLEN];
    __shared__ float s_w[MAXLEN];
    const float4* emb4 = (const float4*)(embW + (size_t)inp[0] * NHID);
    // scores: 16 waves cover 24 rows
    for (int i = wave; i < MAXLEN; i += 16) {
        const float4* w4 = (const float4*)(attnW + (size_t)i * 2 * NHID);
        float acc = 0.f;
        #pragma unroll
        for (int it = 0; it < 8; ++it) {
            int idx = it * 64 + lane;                     // [0,512) float4
            float4 w = w4[idx];
            float4 a = (idx < 256) ? emb4[idx] : hid4[idx - 256];
            acc += w.x * a.x + w.y * a.y + w.z * a.z + w.w * a.w;
        }
        acc = wave_reduce_sum(acc);
        if (lane == 0) s_sc[i] = acc + attnb[i];
    }
    __syncthreads();
    if (tid == 0) {
        float m = -1e30f;
        for (int i = 0; i < MAXLEN; ++i) m = fmaxf(m, s_sc[i]);
        float s = 0.f;
        for (int i = 0; i < MAXLEN; ++i) { float e = expf(s_sc[i] - m); s_w[i] = e; s += e; }
        float inv = 1.f / s;
        for (int i = 0; i < MAXLEN; ++i) { s_w[i] *= inv; out[NOUT + NHID + i] = s_w[i]; }
    }
    __syncthreads();
    {   // applied: thread j computes attn_applied[j]
        float acc = 0.f;
        #pragma unroll 4
        for (int i = 0; i < MAXLEN; ++i) acc += s_w[i] * enc[i * NHID + tid];
        ws[WS_APP + tid] = acc;
    }
}

// K2: x[j] = relu(dot(concat(emb, applied), comb_W[j]) + comb_b[j]).
__global__ __launch_bounds__(256) void
k_comb(const int* __restrict__ inp, const float* __restrict__ embW,
       const float* __restrict__ combW, const float* __restrict__ combb,
       float* __restrict__ ws) {
    const int j = blockIdx.x, t = threadIdx.x;
    const float4* emb4 = (const float4*)(embW + (size_t)inp[0] * NHID);
    const float4* app4 = (const float4*)(ws + WS_APP);
    const float4* w4 = (const float4*)(combW + (size_t)j * 2 * NHID);
    float4 wa = w4[t],       xa = emb4[t];
    float4 wb = w4[256 + t], xb = app4[t];
    float p = wa.x * xa.x + wa.y * xa.y + wa.z * xa.z + wa.w * xa.w
            + wb.x * xb.x + wb.y * xb.y + wb.z * xb.z + wb.w * xb.w;
    p = wave_reduce_sum(p);
    __shared__ float s_r[4];
    if ((t & 63) == 0) s_r[t >> 6] = p;
    __syncthreads();
    if (t == 0) ws[WS_X + j] = fmaxf(s_r[0] + s_r[1] + s_r[2] + s_r[3] + combb[j], 0.f);
}

// K3: gi rows for index j + elementwise GRU combine (gh precomputed in K1).
__global__ __launch_bounds__(256) void
k_gru(const float* __restrict__ hid, const float* __restrict__ Wih,
      const float* __restrict__ bih, float* __restrict__ ws,
      float* __restrict__ out) {
    const int j = blockIdx.x, t = threadIdx.x;
    const float4* x4 = (const float4*)(ws + WS_X);
    float4 xv = x4[t];
    float p[3];
    #pragma unroll
    for (int r = 0; r < 3; ++r) {
        float4 wv = ((const float4*)(Wih + (size_t)(r * NHID + j) * NHID))[t];
        p[r] = wv.x * xv.x + wv.y * xv.y + wv.z * xv.z + wv.w * xv.w;
    }
    __shared__ float s_r[3][4];
    #pragma unroll
    for (int r = 0; r < 3; ++r) {
        float v = wave_reduce_sum(p[r]);
        if ((t & 63) == 0) s_r[r][t >> 6] = v;
    }
    __syncthreads();
    if (t == 0) {
        float gi[3];
        #pragma unroll
        for (int r = 0; r < 3; ++r) gi[r] = s_r[r][0] + s_r[r][1] + s_r[r][2] + s_r[r][3] + bih[r * NHID + j];
        float hr = ws[WS_GH + j], hz = ws[WS_GH + NHID + j], hn = ws[WS_GH + 2 * NHID + j];
        float r_ = 1.f / (1.f + expf(-(gi[0] + hr)));
        float z_ = 1.f / (1.f + expf(-(gi[1] + hz)));
        float n_ = tanhf(gi[2] + r_ * hn);
        float hnew = (1.f - z_) * n_ + z_ * hid[j];
        ws[WS_H + j] = hnew;
        out[NOUT + j] = hnew;
    }
}

// K4: logits + per-block online-LSE pair. 16 waves/block, 4 rows/wave.
// All 16 weight loads (256 B/lane) issued before any reduction.
__global__ __launch_bounds__(1024) void
k_logits(const float* __restrict__ outW, const float* __restrict__ outb,
         float* __restrict__ ws) {
    const int tid = threadIdx.x;
    const int lane = tid & 63, wave = tid >> 6;
    const float4* h4 = (const float4*)(ws + WS_H);
    float4 hv[4];
    #pragma unroll
    for (int it = 0; it < 4; ++it) hv[it] = h4[it * 64 + lane];

    const int rowBase = blockIdx.x * 64 + wave * 4;
    float4 w[4][4];
    #pragma unroll
    for (int rr = 0; rr < 4; ++rr) {
        int row = rowBase + rr;
        if (row >= NOUT) row = NOUT - 1;       // clamp: duplicate loads, discarded later
        const float4* w4 = (const float4*)(outW + (size_t)row * NHID);
        #pragma unroll
        for (int it = 0; it < 4; ++it) w[rr][it] = w4[it * 64 + lane];
    }
    float acc[4];
    #pragma unroll
    for (int rr = 0; rr < 4; ++rr) {
        float a = 0.f;
        #pragma unroll
        for (int it = 0; it < 4; ++it)
            a += w[rr][it].x * hv[it].x + w[rr][it].y * hv[it].y
               + w[rr][it].z * hv[it].z + w[rr][it].w * hv[it].w;
        acc[rr] = a;
    }
    #pragma unroll
    for (int rr = 0; rr < 4; ++rr) acc[rr] = wave_reduce_sum(acc[rr]);

    float m = -1e30f, s = 0.f;
    if (lane == 0) {
        #pragma unroll
        for (int rr = 0; rr < 4; ++rr) {
            const int row = rowBase + rr;
            if (row < NOUT) {
                float v = acc[rr] + outb[row];
                ws[WS_LOGIT + row] = v;
                lse_merge(m, s, v, 1.f);
            }
        }
    }
    __shared__ float sm[16], ss[16];
    if (lane == 0) { sm[wave] = m; ss[wave] = s; }
    __syncthreads();
    if (tid == 0) {
        float M = sm[0], S = ss[0];
        #pragma unroll
        for (int w2 = 1; w2 < 16; ++w2) lse_merge(M, S, sm[w2], ss[w2]);
        ws[WS_PAIRS + 2 * blockIdx.x] = M;
        ws[WS_PAIRS + 2 * blockIdx.x + 1] = S;
    }
}

// K5: every block merges all pairs -> C, then normalizes its slice.
__global__ __launch_bounds__(1024) void
k_finalize(const float* __restrict__ ws, float* __restrict__ out) {
    const int tid = threadIdx.x;
    const int lane = tid & 63, wave = tid >> 6;
    float m = -1e30f, s = 0.f;
    if (tid < LOG_BLOCKS) { m = ws[WS_PAIRS + 2 * tid]; s = ws[WS_PAIRS + 2 * tid + 1]; }
    #pragma unroll
    for (int off = 32; off > 0; off >>= 1) {
        float m2 = __shfl_down(m, off, 64);
        float s2 = __shfl_down(s, off, 64);
        lse_merge(m, s, m2, s2);
    }
    __shared__ float sm[16], ss[16];
    __shared__ float sC;
    if (lane == 0) { sm[wave] = m; ss[wave] = s; }
    __syncthreads();
    if (tid == 0) {
        float M = sm[0], S = ss[0];
        #pragma unroll
        for (int w = 1; w < 16; ++w) lse_merge(M, S, sm[w], ss[w]);
        sC = M + logf(S);
    }
    __syncthreads();
    const float C = sC;
    const int i = blockIdx.x * 1024 + tid;
    if (i < NOUT) out[i] = ws[WS_LOGIT + i] - C;
}

extern "C" void kernel_launch(void* const* d_in, const int* in_sizes, int n_in,
                              void* d_out, int out_size, void* d_ws, size_t ws_size,
                              hipStream_t stream) {
    const int*   inp   = (const int*)d_in[0];
    const float* hid   = (const float*)d_in[1];
    // d_in[2] (encoder_output) unused by the reference.
    const float* enc   = (const float*)d_in[3];
    const float* embW  = (const float*)d_in[4];
    const float* attnW = (const float*)d_in[5];
    const float* attnb = (const float*)d_in[6];
    const float* combW = (const float*)d_in[7];
    const float* combb = (const float*)d_in[8];
    const float* Wih   = (const float*)d_in[9];
    const float* Whh   = (const float*)d_in[10];
    const float* bih   = (const float*)d_in[11];
    const float* bhh   = (const float*)d_in[12];
    const float* outW  = (const float*)d_in[13];
    const float* outb  = (const float*)d_in[14];
    float* out = (float*)d_out;
    float* ws  = (float*)d_ws;

    hipLaunchKernelGGL(k_attn_gh, dim3(1 + 192), dim3(1024), 0, stream,
                       inp, hid, enc, embW, attnW, attnb, Whh, bhh, ws, out);
    hipLaunchKernelGGL(k_comb, dim3(NHID), dim3(256), 0, stream,
                       inp, embW, combW, combb, ws);
    hipLaunchKernelGGL(k_gru, dim3(NHID), dim3(256), 0, stream,
                       hid, Wih, bih, ws, out);
    hipLaunchKernelGGL(k_logits, dim3(LOG_BLOCKS), dim3(1024), 0, stream,
                       outW, outb, ws);
    hipLaunchKernelGGL(k_finalize, dim3(50), dim3(1024), 0, stream,
                       ws, out);
}